// Round 14
// baseline (923.821 us; speedup 1.0000x reference)
//
#include <hip/hip_runtime.h>
#include <hip/hip_bf16.h>
#include <math.h>

// Problem constants (match reference)
#define B_   1024
#define L_   50
#define E_   20
#define N_   20
#define WD_  300
#define ED_  100
#define MD_  400
#define QD_  200
#define H_   20
#define DK_  20

// KGAT v9 geometry: 8 groups (160 rows)/block, 320 threads (5 waves),
// wave owns 2 M-tiles; 5 N-passes of 5 tiles; A-frags hoisted in registers.
#define G8    8
#define MR8   160        // G8*N_
#define KS3   7          // k-steps (224 = 7*32)

// QKV-MFMA geometry
#define KP2   128    // K=100 padded to 4*32
#define KP3   256    // LDS row stride (ushort) for swizzled 224-col tiles
#define QKV_NT 75    // 3 * 25 N-tiles
#define QKV_KS 4

// word-branch MFMA geometry
#define KPW   320    // wlin LDS row stride u16 (300 pad 320, 40 granules)
#define KPA   448    // watt LDS row stride u16 (400 pad 416, read stride 448)

typedef __bf16 bf8_t __attribute__((ext_vector_type(8)));
typedef float  f32x4 __attribute__((ext_vector_type(4)));

__device__ __forceinline__ unsigned short f2bf(float f) {
    __hip_bfloat16 h = __float2bfloat16(f);
    return *reinterpret_cast<unsigned short*>(&h);
}
__device__ __forceinline__ float bf2f(unsigned short u) {
    return __uint_as_float(((unsigned int)u) << 16);
}
__device__ __forceinline__ unsigned pk2(float a, float b) {
    return (unsigned)f2bf(a) | ((unsigned)f2bf(b) << 16);
}
// swizzled ushort index, KP2-col tile
__device__ __forceinline__ int swz2(int r, int k) {
    return r * KP2 + ((((k >> 3) ^ (r & 7)) << 3) | (k & 7));
}
// swizzled ushort index, KP3-col tile
__device__ __forceinline__ int swz3(int r, int k) {
    return r * KP3 + ((((k >> 3) ^ (r & 7)) << 3) | (k & 7));
}

// ---------------------------------------------------------------------------
// K1a: pack Ww1 [300][100] -> B-frags. nt 0..7 (N pad 128), ks 0..9 (K pad 320)
// ---------------------------------------------------------------------------
__global__ __launch_bounds__(64) void k_pack_wlin(const float* __restrict__ Ww1,
                                                  unsigned short* __restrict__ Bp) {
    int nt = blockIdx.x, ks = blockIdx.y, lane = threadIdx.x;
    int col = nt * 16 + (lane & 15);
    int k0 = ks * 32 + (lane >> 4) * 8;
    unsigned short v[8];
    #pragma unroll
    for (int j = 0; j < 8; ++j) {
        int k = k0 + j;
        v[j] = (col < 100 && k < 300) ? f2bf(Ww1[(size_t)k * 100 + col]) : (unsigned short)0;
    }
    *(bf8_t*)(Bp + ((size_t)(nt * 10 + ks) * 64 + lane) * 8) = *(const bf8_t*)v;
}

// ---------------------------------------------------------------------------
// K1b: h = tanh(we @ Ww1 + bw1) -> bf16 via MFMA. M=64 rows/block (800 blocks).
// ---------------------------------------------------------------------------
__global__ __launch_bounds__(256) void k_wlin_mfma(const float* __restrict__ we,
                                                   const unsigned short* __restrict__ Bp,
                                                   const float* __restrict__ bw1,
                                                   unsigned short* __restrict__ h) {
    __shared__ unsigned short Xs[64 * KPW];   // 40 KB
    int t = threadIdx.x;
    int R0 = blockIdx.x * 64;
    for (int u = t; u < 64 * 40; u += 256) {
        int r = u / 40, gl = u % 40;
        const float* src = we + (size_t)(R0 + r) * 300 + gl * 8;
        uint4 w = make_uint4(0u, 0u, 0u, 0u);
        if (gl < 37) {
            float4 f0 = *(const float4*)(src);
            float4 f1 = *(const float4*)(src + 4);
            w.x = pk2(f0.x, f0.y); w.y = pk2(f0.z, f0.w);
            w.z = pk2(f1.x, f1.y); w.w = pk2(f1.z, f1.w);
        } else if (gl == 37) {
            float4 f0 = *(const float4*)(src);   // cols 296..299
            w.x = pk2(f0.x, f0.y); w.y = pk2(f0.z, f0.w);
        }
        *(uint4*)&Xs[r * KPW + ((gl ^ (r & 7)) << 3)] = w;
    }
    __syncthreads();

    int wv = t >> 6, lane = t & 63, lr = lane & 15, lq = lane >> 4;
    f32x4 acc[4][2];
    #pragma unroll
    for (int mi = 0; mi < 4; ++mi)
        #pragma unroll
        for (int c = 0; c < 2; ++c) acc[mi][c] = (f32x4){0.f, 0.f, 0.f, 0.f};
    for (int ks = 0; ks < 10; ++ks) {
        bf8_t a[4], b[2];
        #pragma unroll
        for (int mi = 0; mi < 4; ++mi) {
            int r = mi * 16 + lr;
            int g = (ks * 4 + lq) ^ (r & 7);
            a[mi] = *(const bf8_t*)&Xs[r * KPW + g * 8];
        }
        #pragma unroll
        for (int c = 0; c < 2; ++c) {
            int nt = wv * 2 + c;
            b[c] = *(const bf8_t*)(Bp + ((size_t)(nt * 10 + ks) * 64 + lane) * 8);
        }
        #pragma unroll
        for (int mi = 0; mi < 4; ++mi)
            #pragma unroll
            for (int c = 0; c < 2; ++c)
                acc[mi][c] = __builtin_amdgcn_mfma_f32_16x16x32_bf16(a[mi], b[c], acc[mi][c], 0, 0, 0);
    }
    #pragma unroll
    for (int c = 0; c < 2; ++c) {
        int col = (wv * 2 + c) * 16 + lr;
        if (col < 100) {
            float bb = bw1[col];
            #pragma unroll
            for (int mi = 0; mi < 4; ++mi) {
                #pragma unroll
                for (int j = 0; j < 4; ++j) {
                    int row = R0 + mi * 16 + lq * 4 + j;
                    h[(size_t)row * 100 + col] = f2bf(tanhf(acc[mi][c][j] + bb));
                }
            }
        }
    }
}

// ---------------------------------------------------------------------------
// K2a: pack [Wq|Wk|Wv] into mfma B-fragment layout, K padded 100->128.
// ---------------------------------------------------------------------------
__global__ __launch_bounds__(64) void k_pack_qkv(const float* __restrict__ Wq,
                                                 const float* __restrict__ Wk,
                                                 const float* __restrict__ Wv,
                                                 unsigned short* __restrict__ Bp) {
    int nt = blockIdx.x;        // 0..74
    int ks = blockIdx.y;        // 0..3
    int lane = threadIdx.x;
    int p = nt / 25;
    int cm = (nt % 25) * 16 + (lane & 15);
    int k0 = ks * 32 + (lane >> 4) * 8;
    const float* W = (p == 0) ? Wq : (p == 1) ? Wk : Wv;
    unsigned short v[8];
    #pragma unroll
    for (int j = 0; j < 8; ++j) {
        int k = k0 + j;
        v[j] = (k < 100) ? f2bf(W[(size_t)k * MD_ + cm]) : (unsigned short)0;
    }
    unsigned short* dst = Bp + ((size_t)(nt * QKV_KS + ks) * 64 + lane) * 8;
    *(bf8_t*)dst = *(const bf8_t*)v;
}

// ---------------------------------------------------------------------------
// K2a': pack a row-slice of A1 into B-fragment layout.
// ---------------------------------------------------------------------------
__global__ __launch_bounds__(64) void k_pack_A1part(const float* __restrict__ A1,
                                                    unsigned short* __restrict__ Bp,
                                                    int rowoff, int rowcnt) {
    int nt = blockIdx.x;        // 0..24
    int ks = blockIdx.y;
    int KSn = gridDim.y;
    int lane = threadIdx.x;
    int n  = nt * 16 + (lane & 15);
    int k0 = ks * 32 + (lane >> 4) * 8;
    unsigned short v[8];
    #pragma unroll
    for (int j = 0; j < 8; ++j) {
        int k = k0 + j;
        v[j] = (k < rowcnt) ? f2bf(A1[(size_t)(rowoff + k) * MD_ + n]) : (unsigned short)0;
    }
    unsigned short* dst = Bp + ((size_t)(nt * KSn + ks) * 64 + lane) * 8;
    *(bf8_t*)dst = *(const bf8_t*)v;
}

// ---------------------------------------------------------------------------
// K2a'': pack We1 [200][100] -> B-frags (ent cols 0..99, agg cols 112..211)
// ---------------------------------------------------------------------------
__global__ __launch_bounds__(64) void k_pack_We1(const float* __restrict__ We1,
                                                 unsigned short* __restrict__ Bp) {
    int nt = blockIdx.x;        // 0..6
    int ks = blockIdx.y;        // 0..6
    int lane = threadIdx.x;
    int n  = nt * 16 + (lane & 15);
    int k0 = ks * 32 + (lane >> 4) * 8;
    unsigned short v[8];
    #pragma unroll
    for (int j = 0; j < 8; ++j) {
        int k = k0 + j;
        float f = 0.f;
        if (n < 100) {
            if (k < 100)                 f = We1[(size_t)k * 100 + n];
            else if (k >= 112 && k < 212) f = We1[(size_t)(k - 12) * 100 + n];
        }
        v[j] = f2bf(f);
    }
    unsigned short* dst = Bp + ((size_t)(nt * 7 + ks) * 64 + lane) * 8;
    *(bf8_t*)dst = *(const bf8_t*)v;
}

// ---------------------------------------------------------------------------
// K2a''': pack Wwa [400][200] -> B-frags. nt 0..15, ks 0..12 (K pad 416).
// ---------------------------------------------------------------------------
__global__ __launch_bounds__(64) void k_pack_wwa(const float* __restrict__ Wwa,
                                                 unsigned short* __restrict__ Bp) {
    int nt = blockIdx.x, ks = blockIdx.y, lane = threadIdx.x;
    int col = nt * 16 + (lane & 15);
    int k0 = ks * 32 + (lane >> 4) * 8;
    unsigned short v[8];
    #pragma unroll
    for (int j = 0; j < 8; ++j) {
        int k = k0 + j;
        v[j] = (col < QD_ && k < 400) ? f2bf(Wwa[(size_t)k * QD_ + col]) : (unsigned short)0;
    }
    *(bf8_t*)(Bp + ((size_t)(nt * 13 + ks) * 64 + lane) * 8) = *(const bf8_t*)v;
}

// ---------------------------------------------------------------------------
// K2b: QKV GEMM via MFMA. Output bf16 [B][H][DK][L]; q pre-scaled.
// ---------------------------------------------------------------------------
__global__ __launch_bounds__(320) void k_qkv(const unsigned short* __restrict__ hbf,
                                             const unsigned short* __restrict__ Bp,
                                             const float* __restrict__ bq,
                                             const float* __restrict__ bk,
                                             const float* __restrict__ bv,
                                             unsigned short* __restrict__ qo,
                                             unsigned short* __restrict__ ko,
                                             unsigned short* __restrict__ vo) {
    __shared__ unsigned short Xs[64 * KP2];   // 16 KB
    int t = threadIdx.x;
    int R0 = blockIdx.x * 64;
    for (int i = t; i < 64 * 100; i += 320) {
        int r = i / 100, k = i % 100;
        Xs[swz2(r, k)] = hbf[(size_t)(R0 + r) * 100 + k];
    }
    for (int i = t; i < 64 * 28; i += 320) {
        int r = i / 28, k = 100 + i % 28;
        Xs[swz2(r, k)] = 0;
    }
    __syncthreads();

    int wv = t >> 6, lane = t & 63, lr = lane & 15, lq = lane >> 4;
    bf8_t A[4][4];
    #pragma unroll
    for (int ks = 0; ks < 4; ++ks)
        #pragma unroll
        for (int mi = 0; mi < 4; ++mi) {
            int r = mi * 16 + lr;
            int g = (ks * 4 + lq) ^ (r & 7);
            A[ks][mi] = *(const bf8_t*)&Xs[r * KP2 + g * 8];
        }

    const float scaleq = 0.22360679774997896f;  // 1/sqrt(20)
    #pragma unroll
    for (int p = 0; p < 3; ++p) {
        f32x4 acc[4][5];
        #pragma unroll
        for (int mi = 0; mi < 4; ++mi)
            #pragma unroll
            for (int nj = 0; nj < 5; ++nj)
                acc[mi][nj] = (f32x4){0.f, 0.f, 0.f, 0.f};
        #pragma unroll
        for (int ks = 0; ks < 4; ++ks) {
            bf8_t b[5];
            #pragma unroll
            for (int nj = 0; nj < 5; ++nj) {
                const unsigned short* bp = Bp + ((size_t)((p * 25 + wv * 5 + nj) * QKV_KS + ks) * 64 + lane) * 8;
                b[nj] = *(const bf8_t*)bp;
            }
            #pragma unroll
            for (int mi = 0; mi < 4; ++mi)
                #pragma unroll
                for (int nj = 0; nj < 5; ++nj)
                    acc[mi][nj] = __builtin_amdgcn_mfma_f32_16x16x32_bf16(A[ks][mi], b[nj], acc[mi][nj], 0, 0, 0);
        }
        const float* bias = (p == 0) ? bq : (p == 1) ? bk : bv;
        unsigned short* op = (p == 0) ? qo : (p == 1) ? ko : vo;
        #pragma unroll
        for (int nj = 0; nj < 5; ++nj) {
            int cm = (wv * 5 + nj) * 16 + lr;
            int hh = cm / 20, dk = cm % 20;
            float bb = bias[cm];
            #pragma unroll
            for (int mi = 0; mi < 4; ++mi) {
                int Rq = R0 + mi * 16 + lq * 4;   // 4 consecutive rows
                int b  = Rq / 50, l0 = Rq - b * 50;
                float vle[4];
                #pragma unroll
                for (int j = 0; j < 4; ++j) {
                    float x = acc[mi][nj][j] + bb;
                    vle[j] = (p == 0) ? x * scaleq : x;
                }
                if (l0 <= 46) {
                    size_t base = (((size_t)b * H_ + hh) * DK_ + dk) * (size_t)L_ + l0;
                    unsigned int u0 = (unsigned int)f2bf(vle[0]) | ((unsigned int)f2bf(vle[1]) << 16);
                    unsigned int u1 = (unsigned int)f2bf(vle[2]) | ((unsigned int)f2bf(vle[3]) << 16);
                    *(unsigned int*)(op + base)     = u0;
                    *(unsigned int*)(op + base + 2) = u1;
                } else {
                    #pragma unroll
                    for (int j = 0; j < 4; ++j) {
                        int R = Rq + j;
                        int bj = R / 50, lj = R - bj * 50;
                        op[(((size_t)bj * H_ + hh) * DK_ + dk) * (size_t)L_ + lj] = f2bf(vle[j]);
                    }
                }
            }
        }
    }
}

// ---------------------------------------------------------------------------
// K2c: attention, single-pass (scores ~0.2, exp without max-shift is safe).
// ---------------------------------------------------------------------------
__global__ __launch_bounds__(256) void k_attn(const unsigned short* __restrict__ q,
                                              const unsigned short* __restrict__ k,
                                              const unsigned short* __restrict__ v,
                                              unsigned short* __restrict__ mh) {
    __shared__ float ks_[4][DK_][L_ + 2];
    __shared__ float vs_[4][DK_][L_ + 2];
    int t = threadIdx.x, wv = t >> 6, lane = t & 63;
    int bh = blockIdx.x * 4 + wv;
    int bl = bh / H_, hh = bh % H_;
    size_t base = (size_t)bh * (DK_ * L_); // [bl][hh][j][l] flat
    for (int i4 = lane * 4; i4 < DK_ * L_; i4 += 256) {
        uint2 kw = *(const uint2*)(k + base + i4);
        uint2 vw = *(const uint2*)(v + base + i4);
        unsigned short ku[4] = {(unsigned short)kw.x, (unsigned short)(kw.x >> 16),
                                (unsigned short)kw.y, (unsigned short)(kw.y >> 16)};
        unsigned short vu[4] = {(unsigned short)vw.x, (unsigned short)(vw.x >> 16),
                                (unsigned short)vw.y, (unsigned short)(vw.y >> 16)};
        #pragma unroll
        for (int e = 0; e < 4; ++e) {
            int idx = i4 + e;
            int j = idx / L_, m = idx - j * L_;
            ks_[wv][j][m] = bf2f(ku[e]);
            vs_[wv][j][m] = bf2f(vu[e]);
        }
    }
    int l = (lane < L_) ? lane : (L_ - 1);
    float qr[20];
    #pragma unroll
    for (int j = 0; j < DK_; ++j)
        qr[j] = bf2f(q[base + j * L_ + l]);
    __syncthreads();

    float sum = 0.f;
    float acc[20];
    #pragma unroll
    for (int j = 0; j < DK_; ++j) acc[j] = 0.f;
    #pragma unroll 2
    for (int m = 0; m < L_; ++m) {
        float a0 = 0.f, a1 = 0.f;
        #pragma unroll
        for (int j = 0; j < DK_; j += 2) {
            a0 = fmaf(qr[j],     ks_[wv][j][m],     a0);
            a1 = fmaf(qr[j + 1], ks_[wv][j + 1][m], a1);
        }
        float e = __expf(a0 + a1);
        sum += e;
        #pragma unroll
        for (int j = 0; j < DK_; ++j)
            acc[j] = fmaf(e, vs_[wv][j][m], acc[j]);
    }
    float inv = 1.f / sum;
    if (lane < L_) {
        unsigned int w_[10];
        #pragma unroll
        for (int j2 = 0; j2 < 10; ++j2) {
            unsigned short u0 = f2bf(tanhf(acc[j2 * 2] * inv));
            unsigned short u1 = f2bf(tanhf(acc[j2 * 2 + 1] * inv));
            w_[j2] = (unsigned int)u0 | ((unsigned int)u1 << 16);
        }
        unsigned short* dst = mh + ((size_t)bl * L_ + l) * MD_ + hh * DK_;
        uint2* d2 = (uint2*)dst;
        #pragma unroll
        for (int i = 0; i < 5; ++i) d2[i] = make_uint2(w_[2 * i], w_[2 * i + 1]);
    }
}

// ---------------------------------------------------------------------------
// K3: word additive attention via MFMA (unchanged)
// ---------------------------------------------------------------------------
__global__ __launch_bounds__(256) void k_watt_mfma(const unsigned short* __restrict__ mh,
                                                   const unsigned short* __restrict__ Bwa,
                                                   const float* __restrict__ bwa,
                                                   const float* __restrict__ qwa,
                                                   float* __restrict__ word_rep) {
    __shared__ unsigned short Xs[64 * KPA];   // 57.3 KB
    __shared__ float att2[64];
    __shared__ float alpha_s[64];
    int t = threadIdx.x;
    int b = blockIdx.x;
    for (int u = t; u < 64 * 52; u += 256) {
        int r = u / 52, gl = u % 52;
        uint4 w = make_uint4(0u, 0u, 0u, 0u);
        if (r < 50 && gl < 50)
            w = *(const uint4*)(mh + (size_t)b * (L_ * MD_) + r * MD_ + gl * 8);
        *(uint4*)&Xs[r * KPA + ((gl ^ (r & 7)) << 3)] = w;
    }
    if (t < 64) att2[t] = 0.f;
    __syncthreads();

    int wv = t >> 6, lane = t & 63, lr = lane & 15, lq = lane >> 4;
    f32x4 acc[4][4];
    #pragma unroll
    for (int mi = 0; mi < 4; ++mi)
        #pragma unroll
        for (int c = 0; c < 4; ++c) acc[mi][c] = (f32x4){0.f, 0.f, 0.f, 0.f};

    for (int ks = 0; ks < 13; ++ks) {
        bf8_t a[4], bb[4];
        #pragma unroll
        for (int mi = 0; mi < 4; ++mi) {
            int r = mi * 16 + lr;
            int g = (ks * 4 + lq) ^ (r & 7);
            a[mi] = *(const bf8_t*)&Xs[r * KPA + g * 8];
        }
        #pragma unroll
        for (int c = 0; c < 4; ++c) {
            int nt = wv * 4 + c;
            bb[c] = *(const bf8_t*)(Bwa + ((size_t)(nt * 13 + ks) * 64 + lane) * 8);
        }
        #pragma unroll
        for (int mi = 0; mi < 4; ++mi)
            #pragma unroll
            for (int c = 0; c < 4; ++c)
                acc[mi][c] = __builtin_amdgcn_mfma_f32_16x16x32_bf16(a[mi], bb[c], acc[mi][c], 0, 0, 0);
    }

    float pr[4][4];
    #pragma unroll
    for (int mi = 0; mi < 4; ++mi)
        #pragma unroll
        for (int j = 0; j < 4; ++j) pr[mi][j] = 0.f;
    #pragma unroll
    for (int c = 0; c < 4; ++c) {
        int col = (wv * 4 + c) * 16 + lr;
        float bv = (col < QD_) ? bwa[col] : 0.f;
        float qv = (col < QD_) ? qwa[col] : 0.f;
        #pragma unroll
        for (int mi = 0; mi < 4; ++mi) {
            #pragma unroll
            for (int j = 0; j < 4; ++j)
                pr[mi][j] = fmaf(tanhf(acc[mi][c][j] + bv), qv, pr[mi][j]);
        }
    }
    #pragma unroll
    for (int mi = 0; mi < 4; ++mi) {
        #pragma unroll
        for (int j = 0; j < 4; ++j) {
            float v = pr[mi][j];
            v += __shfl_xor(v, 1); v += __shfl_xor(v, 2);
            v += __shfl_xor(v, 4); v += __shfl_xor(v, 8);
            if (lr == 0) atomicAdd(&att2[mi * 16 + lq * 4 + j], v);
        }
    }
    __syncthreads();
    if (t == 0) {
        float mx = -1e30f;
        for (int l = 0; l < L_; ++l) mx = fmaxf(mx, att2[l]);
        float s = 0.f;
        for (int l = 0; l < L_; ++l) { float e = expf(att2[l] - mx); alpha_s[l] = e; s += e; }
        float inv = 1.f / s;
        for (int l = 0; l < L_; ++l) alpha_s[l] *= inv;
    }
    __syncthreads();
    for (int d = t; d < MD_; d += 256) {
        int glb = (d >> 3), jd = d & 7;
        float a = 0.f;
        for (int l = 0; l < L_; ++l)
            a = fmaf(alpha_s[l], bf2f(Xs[l * KPA + ((glb ^ (l & 7)) << 3) + jd]), a);
        word_rep[(size_t)b * MD_ + d] = a;
    }
}

// ---------------------------------------------------------------------------
// K5a: hAb[ge][c] = ent[ge] @ A1[0:100] + a1b   (MFMA, M=64 rows/block)
// ---------------------------------------------------------------------------
__global__ __launch_bounds__(320) void k_hab(const float* __restrict__ ent_emb,
                                             const unsigned short* __restrict__ Bh,
                                             const float* __restrict__ a1b,
                                             float* __restrict__ hAb) {
    __shared__ unsigned short Xs[64 * KP2];   // 16 KB
    int t = threadIdx.x;
    int R0 = blockIdx.x * 64;
    for (int c = t; c < 64 * 25; c += 320) {
        int r = c / 25, d4 = (c % 25) * 4;
        float4 f = *(const float4*)(ent_emb + (size_t)(R0 + r) * 100 + d4);
        uint2 w;
        w.x = pk2(f.x, f.y);
        w.y = pk2(f.z, f.w);
        *(uint2*)&Xs[swz2(r, d4)] = w;
    }
    for (int c = t; c < 64 * 7; c += 320) {
        int r = c / 7, k = 100 + (c % 7) * 4;
        *(uint2*)&Xs[swz2(r, k)] = make_uint2(0u, 0u);
    }
    __syncthreads();

    int wv = t >> 6, lane = t & 63, lr = lane & 15, lq = lane >> 4;
    bf8_t A[4][4];
    #pragma unroll
    for (int ks = 0; ks < 4; ++ks)
        #pragma unroll
        for (int mi = 0; mi < 4; ++mi) {
            int r = mi * 16 + lr;
            int g = (ks * 4 + lq) ^ (r & 7);
            A[ks][mi] = *(const bf8_t*)&Xs[r * KP2 + g * 8];
        }
    f32x4 acc[4][5];
    #pragma unroll
    for (int mi = 0; mi < 4; ++mi)
        #pragma unroll
        for (int nj = 0; nj < 5; ++nj)
            acc[mi][nj] = (f32x4){0.f, 0.f, 0.f, 0.f};
    #pragma unroll
    for (int ks = 0; ks < 4; ++ks) {
        bf8_t b[5];
        #pragma unroll
        for (int nj = 0; nj < 5; ++nj) {
            const unsigned short* bp = Bh + ((size_t)((wv * 5 + nj) * 4 + ks) * 64 + lane) * 8;
            b[nj] = *(const bf8_t*)bp;
        }
        #pragma unroll
        for (int mi = 0; mi < 4; ++mi)
            #pragma unroll
            for (int nj = 0; nj < 5; ++nj)
                acc[mi][nj] = __builtin_amdgcn_mfma_f32_16x16x32_bf16(A[ks][mi], b[nj], acc[mi][nj], 0, 0, 0);
    }
    #pragma unroll
    for (int nj = 0; nj < 5; ++nj) {
        int col = (wv * 5 + nj) * 16 + lr;
        float bb = a1b[col];
        #pragma unroll
        for (int mi = 0; mi < 4; ++mi) {
            int row = R0 + mi * 16 + lq * 4;
            #pragma unroll
            for (int j = 0; j < 4; ++j)
                hAb[(size_t)(row + j) * MD_ + col] = acc[mi][nj][j] + bb;
        }
    }
}

// ---------------------------------------------------------------------------
// K5c: KGAT v9 — v8 with HALF-SIZE blocks: 8 groups (160 rows), 320 threads
// (5 waves, wave still owns 2 M-tiles -> same per-wave work/regs ~124), so
// the 2048-reg pool fits 16 waves/CU = 3 resident blocks (vs 1 at 640 thr).
// ---------------------------------------------------------------------------
__global__ __launch_bounds__(320, 3) void k_kgat9(const float* __restrict__ ne,
                                               const float* __restrict__ nr,
                                               const unsigned short* __restrict__ Btr,
                                               const float* __restrict__ hAb,
                                               const float* __restrict__ A2,
                                               float* __restrict__ agg_g) {
    __shared__ float hab_s[G8][MD_];     // 12.8 KB
    __shared__ float att_s[MR8];
    __shared__ float alpha_s[MR8];
    __shared__ float gmx[G8], ginv[G8];
    int t = threadIdx.x;
    int ge0 = blockIdx.x * G8;

    for (int i = t; i < G8 * MD_; i += 320)
        ((float*)hab_s)[i] = hAb[(size_t)ge0 * MD_ + i];
    for (int i = t; i < MR8; i += 320) att_s[i] = 0.f;
    __syncthreads();

    int wv = t >> 6, lane = t & 63;
    int lr = lane & 15, lq = lane >> 4;
    const float* nep[2];
    const float* nrp[2];
    #pragma unroll
    for (int mi = 0; mi < 2; ++mi) {
        int r = (wv * 2 + mi) * 16 + lr;
        int g = (r * 3277) >> 16;            // r/20 for r<320
        int n = r - g * 20;
        size_t rb = ((size_t)(ge0 + g) * N_ + n) * ED_;
        nep[mi] = ne + rb;
        nrp[mi] = nr + rb;
    }
    int k0base = lq * 8;

    // ---- A-fragments loaded ONCE into registers (statically indexed below) ----
    bf8_t Af[2][KS3];
    #pragma unroll
    for (int ks = 0; ks < KS3; ++ks) {
        int k0 = ks * 32 + k0base;
        #pragma unroll
        for (int mi = 0; mi < 2; ++mi) {
            float4 f0, f1;
            if (k0 <= 92) {
                f0 = *(const float4*)(nep[mi] + k0);
                f1 = *(const float4*)(nep[mi] + k0 + 4);
            } else if (k0 == 96) {
                f0 = *(const float4*)(nep[mi] + 96);
                f1 = *(const float4*)(nrp[mi]);
            } else if (k0 <= 192) {
                f0 = *(const float4*)(nrp[mi] + k0 - 100);
                f1 = *(const float4*)(nrp[mi] + k0 - 96);
            } else {
                f0 = make_float4(0.f, 0.f, 0.f, 0.f);
                f1 = f0;
            }
            uint4 uu = make_uint4(pk2(f0.x, f0.y), pk2(f0.z, f0.w),
                                  pk2(f1.x, f1.y), pk2(f1.z, f1.w));
            Af[mi][ks] = *reinterpret_cast<bf8_t*>(&uu);
        }
    }

    #pragma unroll 1
    for (int p = 0; p < 5; ++p) {
        f32x4 acc[2][5];
        #pragma unroll
        for (int mi = 0; mi < 2; ++mi)
            #pragma unroll
            for (int nj = 0; nj < 5; ++nj)
                acc[mi][nj] = (f32x4){0.f, 0.f, 0.f, 0.f};
        #pragma unroll
        for (int ks = 0; ks < KS3; ++ks) {          // FULLY UNROLLED: static Af idx
            bf8_t b[5];
            #pragma unroll
            for (int nj = 0; nj < 5; ++nj) {
                int nt = p * 5 + nj;
                b[nj] = *(const bf8_t*)(Btr + ((size_t)(nt * KS3 + ks) * 64 + lane) * 8);
            }
            #pragma unroll
            for (int mi = 0; mi < 2; ++mi)
                #pragma unroll
                for (int nj = 0; nj < 5; ++nj)
                    acc[mi][nj] = __builtin_amdgcn_mfma_f32_16x16x32_bf16(Af[mi][ks], b[nj], acc[mi][nj], 0, 0, 0);
        }
        // per-pass epilogue: relu -> .A2 -> shfl reduce -> atomicAdd
        float pr[2][4];
        #pragma unroll
        for (int mi = 0; mi < 2; ++mi)
            #pragma unroll
            for (int j = 0; j < 4; ++j) pr[mi][j] = 0.f;
        #pragma unroll
        for (int nj = 0; nj < 5; ++nj) {
            int col = (p * 5 + nj) * 16 + lr;
            float a2v = A2[col];
            #pragma unroll
            for (int mi = 0; mi < 2; ++mi) {
                #pragma unroll
                for (int j = 0; j < 4; ++j) {
                    int row = (wv * 2 + mi) * 16 + lq * 4 + j;
                    int g = (row * 3277) >> 16;
                    float y = acc[mi][nj][j] + hab_s[g][col];
                    pr[mi][j] = fmaf(fmaxf(y, 0.f), a2v, pr[mi][j]);
                }
            }
        }
        #pragma unroll
        for (int mi = 0; mi < 2; ++mi) {
            #pragma unroll
            for (int j = 0; j < 4; ++j) {
                float v = pr[mi][j];
                v += __shfl_xor(v, 1); v += __shfl_xor(v, 2);
                v += __shfl_xor(v, 4); v += __shfl_xor(v, 8);
                if (lr == 0) atomicAdd(&att_s[(wv * 2 + mi) * 16 + lq * 4 + j], v);
            }
        }
    }
    __syncthreads();

    if (t < G8) {
        float mx = -1e30f;
        for (int n = 0; n < N_; ++n) mx = fmaxf(mx, att_s[t * N_ + n]);
        float s = 0.f;
        for (int n = 0; n < N_; ++n) s += expf(att_s[t * N_ + n] - mx);
        gmx[t] = mx; ginv[t] = 1.f / s;
    }
    __syncthreads();
    if (t < MR8) alpha_s[t] = expf(att_s[t] - gmx[t / N_]) * ginv[t / N_];
    __syncthreads();

    // agg[g][d] = sum_n alpha * ne[g][n][d]  (f32 direct, L2-hot)
    for (int i = t; i < G8 * ED_; i += 320) {
        int g = i / ED_, d = i % ED_;
        const float* np = ne + ((size_t)(ge0 + g) * N_) * ED_ + d;
        float aS = 0.f;
        #pragma unroll 4
        for (int n = 0; n < N_; ++n)
            aS = fmaf(alpha_s[g * N_ + n], np[(size_t)n * ED_], aS);
        agg_g[(size_t)(ge0 + g) * ED_ + d] = aS;
    }
}

// ---------------------------------------------------------------------------
// K5d: he = tanh([ent | agg] @ We1 + be1) via MFMA (unchanged)
// ---------------------------------------------------------------------------
__global__ __launch_bounds__(256) void k_he(const float* __restrict__ ent_emb,
                                            const float* __restrict__ agg_g,
                                            const unsigned short* __restrict__ BWe1,
                                            const float* __restrict__ be1,
                                            float* __restrict__ he) {
    __shared__ unsigned short Xs[64 * KP3];   // 32 KB
    int t = threadIdx.x;
    int R0 = blockIdx.x * 64;
    for (int c = t; c < 64 * 25; c += 256) {
        int r = c / 25, d4 = (c % 25) * 4;
        float4 f = *(const float4*)(ent_emb + (size_t)(R0 + r) * 100 + d4);
        uint2 w;
        w.x = pk2(f.x, f.y);
        w.y = pk2(f.z, f.w);
        *(uint2*)&Xs[swz3(r, d4)] = w;
        float4 g = *(const float4*)(agg_g + (size_t)(R0 + r) * 100 + d4);
        uint2 w2;
        w2.x = pk2(g.x, g.y);
        w2.y = pk2(g.z, g.w);
        *(uint2*)&Xs[swz3(r, 112 + d4)] = w2;
    }
    for (int c = t; c < 64 * 6; c += 256) {
        int r = c / 6, z = c % 6;
        int k = (z < 3) ? (100 + z * 4) : (212 + (z - 3) * 4);
        *(uint2*)&Xs[swz3(r, k)] = make_uint2(0u, 0u);
    }
    __syncthreads();

    int wv = t >> 6, lane = t & 63, lr = lane & 15, lq = lane >> 4;
    int rb = wv * 16;
    bf8_t A[7];
    #pragma unroll
    for (int ks = 0; ks < 7; ++ks) {
        int r = rb + lr;
        int g = (ks * 4 + lq) ^ (r & 7);
        A[ks] = *(const bf8_t*)&Xs[r * KP3 + g * 8];
    }
    f32x4 acc[7];
    #pragma unroll
    for (int nt = 0; nt < 7; ++nt) acc[nt] = (f32x4){0.f, 0.f, 0.f, 0.f};
    #pragma unroll
    for (int ks = 0; ks < 7; ++ks) {
        bf8_t b[7];
        #pragma unroll
        for (int nt = 0; nt < 7; ++nt)
            b[nt] = *(const bf8_t*)(BWe1 + ((size_t)(nt * 7 + ks) * 64 + lane) * 8);
        #pragma unroll
        for (int nt = 0; nt < 7; ++nt)
            acc[nt] = __builtin_amdgcn_mfma_f32_16x16x32_bf16(A[ks], b[nt], acc[nt], 0, 0, 0);
    }
    #pragma unroll
    for (int nt = 0; nt < 7; ++nt) {
        int col = nt * 16 + lr;
        if (col < 100) {
            float bb = be1[col];
            #pragma unroll
            for (int j = 0; j < 4; ++j) {
                int row = rb + lq * 4 + j;
                he[(size_t)(R0 + row) * 100 + col] = tanhf(acc[nt][j] + bb);
            }
        }
    }
}

// ---------------------------------------------------------------------------
// K7: fused tail — cat/sub MLPs + entity head + 4-view additive attention.
// ---------------------------------------------------------------------------
__global__ __launch_bounds__(256) void k_fuse_all(
        const float* __restrict__ word_rep, const float* __restrict__ he,
        const float* __restrict__ emb_c, const float* __restrict__ Wc1, const float* __restrict__ bc1,
        const float* __restrict__ Wc2, const float* __restrict__ bc2,
        const float* __restrict__ emb_s, const float* __restrict__ Ws1, const float* __restrict__ bs1,
        const float* __restrict__ Ws2, const float* __restrict__ bs2,
        const float* __restrict__ Wg, const float* __restrict__ bg,
        const float* __restrict__ Wfa, const float* __restrict__ bfa, const float* __restrict__ qfa,
        const int* __restrict__ cat_idx, const int* __restrict__ sub_idx,
        float* __restrict__ out_pre) {
    int b = blockIdx.x;
    __shared__ float reps[4][MD_];
    __shared__ float tin[100], th[100];
    __shared__ float alpha_s[4];
    __shared__ float red[4][4];
    int t = threadIdx.x, wave = t >> 6, lane = t & 63;

    // view 0: word (precomputed)
    for (int i = t; i < MD_; i += 256) reps[0][i] = word_rep[(size_t)b * MD_ + i];
    // view 1: entity = tanh(relu(mean_e(he[b]) @ Wg + bg))
    if (t < 100) {
        float a = 0.f;
        for (int e = 0; e < E_; ++e) a += he[((size_t)b * E_ + e) * ED_ + t];
        tin[t] = a * (1.f / E_);
    }
    __syncthreads();
    for (int m = t; m < MD_; m += 256) {
        float a = bg[m];
        for (int k = 0; k < ED_; ++k) a = fmaf(tin[k], Wg[k * MD_ + m], a);
        reps[1][m] = tanhf(fmaxf(a, 0.f));
    }
    __syncthreads();
    // view 2: category MLP
    if (t < 100) tin[t] = emb_c[(size_t)cat_idx[b] * 100 + t];
    __syncthreads();
    if (t < 100) {
        float a = bc1[t];
        for (int k = 0; k < 100; ++k) a = fmaf(tin[k], Wc1[k * 100 + t], a);
        th[t] = a;
    }
    __syncthreads();
    for (int m = t; m < MD_; m += 256) {
        float a = bc2[m];
        for (int k = 0; k < 100; ++k) a = fmaf(th[k], Wc2[k * MD_ + m], a);
        reps[2][m] = tanhf(a);
    }
    __syncthreads();
    // view 3: subcategory MLP
    if (t < 100) tin[t] = emb_s[(size_t)sub_idx[b] * 100 + t];
    __syncthreads();
    if (t < 100) {
        float a = bs1[t];
        for (int k = 0; k < 100; ++k) a = fmaf(tin[k], Ws1[k * 100 + t], a);
        th[t] = a;
    }
    __syncthreads();
    for (int m = t; m < MD_; m += 256) {
        float a = bs2[m];
        for (int k = 0; k < 100; ++k) a = fmaf(th[k], Ws2[k * MD_ + m], a);
        reps[3][m] = tanhf(a);
    }
    __syncthreads();

    // additive attention over the 4 views
    float p[4] = {0.f, 0.f, 0.f, 0.f};
    if (t < QD_) {
        float acc0 = bfa[t], acc1 = acc0, acc2 = acc0, acc3 = acc0;
        for (int d = 0; d < MD_; ++d) {
            float w = Wfa[d * QD_ + t];
            acc0 = fmaf(reps[0][d], w, acc0);
            acc1 = fmaf(reps[1][d], w, acc1);
            acc2 = fmaf(reps[2][d], w, acc2);
            acc3 = fmaf(reps[3][d], w, acc3);
        }
        float qv = qfa[t];
        p[0] = tanhf(acc0) * qv; p[1] = tanhf(acc1) * qv;
        p[2] = tanhf(acc2) * qv; p[3] = tanhf(acc3) * qv;
    }
    #pragma unroll
    for (int i = 0; i < 4; ++i) {
        float v = p[i];
        for (int o = 32; o > 0; o >>= 1) v += __shfl_down(v, o);
        if (lane == 0) red[i][wave] = v;
    }
    __syncthreads();
    if (t == 0) {
        float a4[4]; float mx = -1e30f;
        #pragma unroll
        for (int i = 0; i < 4; ++i) { a4[i] = red[i][0] + red[i][1] + red[i][2] + red[i][3]; mx = fmaxf(mx, a4[i]); }
        float s = 0.f;
        #pragma unroll
        for (int i = 0; i < 4; ++i) { a4[i] = expf(a4[i] - mx); s += a4[i]; }
        float inv = 1.f / s;
        #pragma unroll
        for (int i = 0; i < 4; ++i) alpha_s[i] = a4[i] * inv;
    }
    __syncthreads();
    for (int m = t; m < MD_; m += 256)
        out_pre[(size_t)b * MD_ + m] = alpha_s[0] * reps[0][m] + alpha_s[1] * reps[1][m]
                                     + alpha_s[2] * reps[2][m] + alpha_s[3] * reps[3][m];
}

// ---------------------------------------------------------------------------
// K8: batchnorm over batch axis (unchanged)
// ---------------------------------------------------------------------------
__global__ __launch_bounds__(256) void k_bn(float* __restrict__ x,
                                            const float* __restrict__ gamma,
                                            const float* __restrict__ beta) {
    int m = blockIdx.x;
    int t = threadIdx.x, wave = t >> 6, lane = t & 63;
    __shared__ float red1[4], red2[4];
    float v[4];
    float s1 = 0.f, s2 = 0.f;
    #pragma unroll
    for (int i = 0; i < 4; ++i) {
        v[i] = x[(size_t)(t + i * 256) * MD_ + m];
        s1 += v[i];
        s2 = fmaf(v[i], v[i], s2);
    }
    for (int o = 32; o > 0; o >>= 1) { s1 += __shfl_down(s1, o); s2 += __shfl_down(s2, o); }
    if (lane == 0) { red1[wave] = s1; red2[wave] = s2; }
    __syncthreads();
    float mean = (red1[0] + red1[1] + red1[2] + red1[3]) * (1.f / 1024.f);
    float var  = (red2[0] + red2[1] + red2[2] + red2[3]) * (1.f / 1024.f) - mean * mean;
    float scale = rsqrtf(var + 1e-5f) * gamma[m];
    float bb = beta[m];
    #pragma unroll
    for (int i = 0; i < 4; ++i)
        x[(size_t)(t + i * 256) * MD_ + m] = (v[i] - mean) * scale + bb;
}

// ---------------------------------------------------------------------------
extern "C" void kernel_launch(void* const* d_in, const int* in_sizes, int n_in,
                              void* d_out, int out_size, void* d_ws, size_t ws_size,
                              hipStream_t stream) {
    const float* word_emb = (const float*)d_in[0];
    const float* ent_emb  = (const float*)d_in[1];
    const float* ne       = (const float*)d_in[2];
    const float* nr       = (const float*)d_in[3];
    const float* emb_c    = (const float*)d_in[4];
    const float* Wc1 = (const float*)d_in[5];
    const float* bc1 = (const float*)d_in[6];
    const float* Wc2 = (const float*)d_in[7];
    const float* bc2 = (const float*)d_in[8];
    const float* emb_s = (const float*)d_in[9];
    const float* Ws1 = (const float*)d_in[10];
    const float* bs1 = (const float*)d_in[11];
    const float* Ws2 = (const float*)d_in[12];
    const float* bs2 = (const float*)d_in[13];
    const float* Ww1 = (const float*)d_in[14];
    const float* bw1 = (const float*)d_in[15];
    const float* Wq  = (const float*)d_in[16];
    const float* bq  = (const float*)d_in[17];
    const float* Wk  = (const float*)d_in[18];
    const float* bk  = (const float*)d_in[19];
    const float* Wv  = (const float*)d_in[20];
    const float* bv  = (const float*)d_in[21];
    const float* Wwa = (const float*)d_in[22];
    const float* bwa = (const float*)d_in[23];
    const float* qwa = (const float*)d_in[24];
    const float* A1  = (const float*)d_in[25];
    const float* a1b = (const float*)d_in[26];
    const float* A2  = (const float*)d_in[27];
    const float* We1 = (const float*)d_in[29];
    const float* be1 = (const float*)d_in[30];
    const float* Wg  = (const float*)d_in[31];
    const float* bg  = (const float*)d_in[32];
    const float* Wfa = (const float*)d_in[36];
    const float* bfa = (const float*)d_in[37];
    const float* qfa = (const float*)d_in[38];
    const float* gamma = (const float*)d_in[39];
    const float* beta  = (const float*)d_in[40];
    const int* cat_idx = (const int*)d_in[41];
    const int* sub_idx = (const int*)d_in[42];

    // workspace (no aliasing; ~190 MB of ~655 MB available)
    char* p = (char*)d_ws;
    float* word_rep = (float*)p;  p += (size_t)B_ * MD_ * 4;               // 1.64 MB
    float* he       = (float*)p;  p += (size_t)B_ * E_ * ED_ * 4;          // 8.19 MB
    float* agg_g    = (float*)p;  p += (size_t)B_ * E_ * ED_ * 4;          // 8.19 MB
    float* hAb      = (float*)p;  p += (size_t)B_ * E_ * MD_ * 4;          // 32.77 MB
    unsigned short* Bqkv  = (unsigned short*)p; p += (size_t)QKV_NT * QKV_KS * 64 * 8 * 2;
    unsigned short* Bh    = (unsigned short*)p; p += (size_t)25 * 4 * 64 * 8 * 2;
    unsigned short* Btr   = (unsigned short*)p; p += (size_t)25 * KS3 * 64 * 8 * 2;
    unsigned short* BWe1  = (unsigned short*)p; p += (size_t)7 * 7 * 64 * 8 * 2;
    unsigned short* Bwlin = (unsigned short*)p; p += (size_t)8 * 10 * 64 * 8 * 2;
    unsigned short* Bwa   = (unsigned short*)p; p += (size_t)16 * 13 * 64 * 8 * 2;
    unsigned short* h_bf  = (unsigned short*)p; p += (size_t)B_ * L_ * 100 * 2;        // 10.24 MB
    unsigned short* qb    = (unsigned short*)p; p += (size_t)B_ * H_ * DK_ * L_ * 2;   // 40.96 MB
    unsigned short* kb    = (unsigned short*)p; p += (size_t)B_ * H_ * DK_ * L_ * 2;
    unsigned short* vb    = (unsigned short*)p; p += (size_t)B_ * H_ * DK_ * L_ * 2;
    unsigned short* mh_bf = (unsigned short*)p; p += (size_t)B_ * L_ * MD_ * 2;        // 40.96 MB
    float* out = (float*)d_out;

    k_pack_qkv<<<dim3(QKV_NT, QKV_KS), 64, 0, stream>>>(Wq, Wk, Wv, Bqkv);
    k_pack_A1part<<<dim3(25, 4), 64, 0, stream>>>(A1, Bh, 0, 100);
    k_pack_A1part<<<dim3(25, KS3), 64, 0, stream>>>(A1, Btr, 100, 200);
    k_pack_We1<<<dim3(7, 7), 64, 0, stream>>>(We1, BWe1);
    k_pack_wlin<<<dim3(8, 10), 64, 0, stream>>>(Ww1, Bwlin);
    k_pack_wwa<<<dim3(16, 13), 64, 0, stream>>>(Wwa, Bwa);
    k_wlin_mfma<<<(B_ * L_) / 64, 256, 0, stream>>>(word_emb, Bwlin, bw1, h_bf);
    k_qkv<<<(B_ * L_) / 64, 320, 0, stream>>>(h_bf, Bqkv, bq, bk, bv, qb, kb, vb);
    k_attn<<<(B_ * H_) / 4, 256, 0, stream>>>(qb, kb, vb, mh_bf);
    k_watt_mfma<<<B_, 256, 0, stream>>>(mh_bf, Bwa, bwa, qwa, word_rep);
    k_hab<<<(B_ * E_) / 64, 320, 0, stream>>>(ent_emb, Bh, a1b, hAb);
    k_kgat9<<<(B_ * E_) / G8, 320, 0, stream>>>(ne, nr, Btr, hAb, A2, agg_g);
    k_he<<<(B_ * E_) / 64, 256, 0, stream>>>(ent_emb, agg_g, BWe1, be1, he);
    k_fuse_all<<<B_, 256, 0, stream>>>(word_rep, he,
                                       emb_c, Wc1, bc1, Wc2, bc2,
                                       emb_s, Ws1, bs1, Ws2, bs2,
                                       Wg, bg, Wfa, bfa, qfa,
                                       cat_idx, sub_idx, out);
    k_bn<<<MD_, 256, 0, stream>>>(out, gamma, beta);
}

// Round 15
// 790.032 us; speedup vs baseline: 1.1693x; 1.1693x over previous
//
#include <hip/hip_runtime.h>
#include <hip/hip_bf16.h>
#include <math.h>

// Problem constants (match reference)
#define B_   1024
#define L_   50
#define E_   20
#define N_   20
#define WD_  300
#define ED_  100
#define MD_  400
#define QD_  200
#define H_   20
#define DK_  20

// KGAT v8 geometry: 16 groups (320 rows)/block, 640 threads, A-frags hoisted
#define G6    16
#define MR6   320        // G6*N_
#define KS3   7          // k-steps (224 = 7*32)

// QKV-MFMA geometry
#define KP2   128    // K=100 padded to 4*32
#define KP3   256    // LDS row stride (ushort) for swizzled 224-col tiles
#define QKV_NT 75    // 3 * 25 N-tiles
#define QKV_KS 4

// word-branch MFMA geometry
#define KPW   320    // wlin LDS row stride u16 (300 pad 320, 40 granules)
#define KPA   448    // watt LDS row stride u16 (400 pad 416, read stride 448)

typedef __bf16 bf8_t __attribute__((ext_vector_type(8)));
typedef float  f32x4 __attribute__((ext_vector_type(4)));

__device__ __forceinline__ unsigned short f2bf(float f) {
    __hip_bfloat16 h = __float2bfloat16(f);
    return *reinterpret_cast<unsigned short*>(&h);
}
__device__ __forceinline__ float bf2f(unsigned short u) {
    return __uint_as_float(((unsigned int)u) << 16);
}
__device__ __forceinline__ unsigned pk2(float a, float b) {
    return (unsigned)f2bf(a) | ((unsigned)f2bf(b) << 16);
}
// swizzled ushort index, KP2-col tile
__device__ __forceinline__ int swz2(int r, int k) {
    return r * KP2 + ((((k >> 3) ^ (r & 7)) << 3) | (k & 7));
}
// swizzled ushort index, KP3-col tile
__device__ __forceinline__ int swz3(int r, int k) {
    return r * KP3 + ((((k >> 3) ^ (r & 7)) << 3) | (k & 7));
}

// ---------------------------------------------------------------------------
// K1a: pack Ww1 [300][100] -> B-frags. nt 0..7 (N pad 128), ks 0..9 (K pad 320)
// ---------------------------------------------------------------------------
__global__ __launch_bounds__(64) void k_pack_wlin(const float* __restrict__ Ww1,
                                                  unsigned short* __restrict__ Bp) {
    int nt = blockIdx.x, ks = blockIdx.y, lane = threadIdx.x;
    int col = nt * 16 + (lane & 15);
    int k0 = ks * 32 + (lane >> 4) * 8;
    unsigned short v[8];
    #pragma unroll
    for (int j = 0; j < 8; ++j) {
        int k = k0 + j;
        v[j] = (col < 100 && k < 300) ? f2bf(Ww1[(size_t)k * 100 + col]) : (unsigned short)0;
    }
    *(bf8_t*)(Bp + ((size_t)(nt * 10 + ks) * 64 + lane) * 8) = *(const bf8_t*)v;
}

// ---------------------------------------------------------------------------
// K1b: h = tanh(we @ Ww1 + bw1) -> bf16 via MFMA. M=64 rows/block (800 blocks).
// ---------------------------------------------------------------------------
__global__ __launch_bounds__(256) void k_wlin_mfma(const float* __restrict__ we,
                                                   const unsigned short* __restrict__ Bp,
                                                   const float* __restrict__ bw1,
                                                   unsigned short* __restrict__ h) {
    __shared__ unsigned short Xs[64 * KPW];   // 40 KB
    int t = threadIdx.x;
    int R0 = blockIdx.x * 64;
    for (int u = t; u < 64 * 40; u += 256) {
        int r = u / 40, gl = u % 40;
        const float* src = we + (size_t)(R0 + r) * 300 + gl * 8;
        uint4 w = make_uint4(0u, 0u, 0u, 0u);
        if (gl < 37) {
            float4 f0 = *(const float4*)(src);
            float4 f1 = *(const float4*)(src + 4);
            w.x = pk2(f0.x, f0.y); w.y = pk2(f0.z, f0.w);
            w.z = pk2(f1.x, f1.y); w.w = pk2(f1.z, f1.w);
        } else if (gl == 37) {
            float4 f0 = *(const float4*)(src);   // cols 296..299
            w.x = pk2(f0.x, f0.y); w.y = pk2(f0.z, f0.w);
        }
        *(uint4*)&Xs[r * KPW + ((gl ^ (r & 7)) << 3)] = w;
    }
    __syncthreads();

    int wv = t >> 6, lane = t & 63, lr = lane & 15, lq = lane >> 4;
    f32x4 acc[4][2];
    #pragma unroll
    for (int mi = 0; mi < 4; ++mi)
        #pragma unroll
        for (int c = 0; c < 2; ++c) acc[mi][c] = (f32x4){0.f, 0.f, 0.f, 0.f};
    for (int ks = 0; ks < 10; ++ks) {
        bf8_t a[4], b[2];
        #pragma unroll
        for (int mi = 0; mi < 4; ++mi) {
            int r = mi * 16 + lr;
            int g = (ks * 4 + lq) ^ (r & 7);
            a[mi] = *(const bf8_t*)&Xs[r * KPW + g * 8];
        }
        #pragma unroll
        for (int c = 0; c < 2; ++c) {
            int nt = wv * 2 + c;
            b[c] = *(const bf8_t*)(Bp + ((size_t)(nt * 10 + ks) * 64 + lane) * 8);
        }
        #pragma unroll
        for (int mi = 0; mi < 4; ++mi)
            #pragma unroll
            for (int c = 0; c < 2; ++c)
                acc[mi][c] = __builtin_amdgcn_mfma_f32_16x16x32_bf16(a[mi], b[c], acc[mi][c], 0, 0, 0);
    }
    #pragma unroll
    for (int c = 0; c < 2; ++c) {
        int col = (wv * 2 + c) * 16 + lr;
        if (col < 100) {
            float bb = bw1[col];
            #pragma unroll
            for (int mi = 0; mi < 4; ++mi) {
                #pragma unroll
                for (int j = 0; j < 4; ++j) {
                    int row = R0 + mi * 16 + lq * 4 + j;
                    h[(size_t)row * 100 + col] = f2bf(tanhf(acc[mi][c][j] + bb));
                }
            }
        }
    }
}

// ---------------------------------------------------------------------------
// K2a: pack [Wq|Wk|Wv] into mfma B-fragment layout, K padded 100->128.
// ---------------------------------------------------------------------------
__global__ __launch_bounds__(64) void k_pack_qkv(const float* __restrict__ Wq,
                                                 const float* __restrict__ Wk,
                                                 const float* __restrict__ Wv,
                                                 unsigned short* __restrict__ Bp) {
    int nt = blockIdx.x;        // 0..74
    int ks = blockIdx.y;        // 0..3
    int lane = threadIdx.x;
    int p = nt / 25;
    int cm = (nt % 25) * 16 + (lane & 15);
    int k0 = ks * 32 + (lane >> 4) * 8;
    const float* W = (p == 0) ? Wq : (p == 1) ? Wk : Wv;
    unsigned short v[8];
    #pragma unroll
    for (int j = 0; j < 8; ++j) {
        int k = k0 + j;
        v[j] = (k < 100) ? f2bf(W[(size_t)k * MD_ + cm]) : (unsigned short)0;
    }
    unsigned short* dst = Bp + ((size_t)(nt * QKV_KS + ks) * 64 + lane) * 8;
    *(bf8_t*)dst = *(const bf8_t*)v;
}

// ---------------------------------------------------------------------------
// K2a': pack a row-slice of A1 into B-fragment layout.
// ---------------------------------------------------------------------------
__global__ __launch_bounds__(64) void k_pack_A1part(const float* __restrict__ A1,
                                                    unsigned short* __restrict__ Bp,
                                                    int rowoff, int rowcnt) {
    int nt = blockIdx.x;        // 0..24
    int ks = blockIdx.y;
    int KSn = gridDim.y;
    int lane = threadIdx.x;
    int n  = nt * 16 + (lane & 15);
    int k0 = ks * 32 + (lane >> 4) * 8;
    unsigned short v[8];
    #pragma unroll
    for (int j = 0; j < 8; ++j) {
        int k = k0 + j;
        v[j] = (k < rowcnt) ? f2bf(A1[(size_t)(rowoff + k) * MD_ + n]) : (unsigned short)0;
    }
    unsigned short* dst = Bp + ((size_t)(nt * KSn + ks) * 64 + lane) * 8;
    *(bf8_t*)dst = *(const bf8_t*)v;
}

// ---------------------------------------------------------------------------
// K2a'': pack We1 [200][100] -> B-frags (ent cols 0..99, agg cols 112..211)
// ---------------------------------------------------------------------------
__global__ __launch_bounds__(64) void k_pack_We1(const float* __restrict__ We1,
                                                 unsigned short* __restrict__ Bp) {
    int nt = blockIdx.x;        // 0..6
    int ks = blockIdx.y;        // 0..6
    int lane = threadIdx.x;
    int n  = nt * 16 + (lane & 15);
    int k0 = ks * 32 + (lane >> 4) * 8;
    unsigned short v[8];
    #pragma unroll
    for (int j = 0; j < 8; ++j) {
        int k = k0 + j;
        float f = 0.f;
        if (n < 100) {
            if (k < 100)                 f = We1[(size_t)k * 100 + n];
            else if (k >= 112 && k < 212) f = We1[(size_t)(k - 12) * 100 + n];
        }
        v[j] = f2bf(f);
    }
    unsigned short* dst = Bp + ((size_t)(nt * 7 + ks) * 64 + lane) * 8;
    *(bf8_t*)dst = *(const bf8_t*)v;
}

// ---------------------------------------------------------------------------
// K2a''': pack Wwa [400][200] -> B-frags. nt 0..15, ks 0..12 (K pad 416).
// ---------------------------------------------------------------------------
__global__ __launch_bounds__(64) void k_pack_wwa(const float* __restrict__ Wwa,
                                                 unsigned short* __restrict__ Bp) {
    int nt = blockIdx.x, ks = blockIdx.y, lane = threadIdx.x;
    int col = nt * 16 + (lane & 15);
    int k0 = ks * 32 + (lane >> 4) * 8;
    unsigned short v[8];
    #pragma unroll
    for (int j = 0; j < 8; ++j) {
        int k = k0 + j;
        v[j] = (col < QD_ && k < 400) ? f2bf(Wwa[(size_t)k * QD_ + col]) : (unsigned short)0;
    }
    *(bf8_t*)(Bp + ((size_t)(nt * 13 + ks) * 64 + lane) * 8) = *(const bf8_t*)v;
}

// ---------------------------------------------------------------------------
// K2b: QKV GEMM via MFMA. Output bf16 [B][H][DK][L]; q pre-scaled.
// ---------------------------------------------------------------------------
__global__ __launch_bounds__(320) void k_qkv(const unsigned short* __restrict__ hbf,
                                             const unsigned short* __restrict__ Bp,
                                             const float* __restrict__ bq,
                                             const float* __restrict__ bk,
                                             const float* __restrict__ bv,
                                             unsigned short* __restrict__ qo,
                                             unsigned short* __restrict__ ko,
                                             unsigned short* __restrict__ vo) {
    __shared__ unsigned short Xs[64 * KP2];   // 16 KB
    int t = threadIdx.x;
    int R0 = blockIdx.x * 64;
    for (int i = t; i < 64 * 100; i += 320) {
        int r = i / 100, k = i % 100;
        Xs[swz2(r, k)] = hbf[(size_t)(R0 + r) * 100 + k];
    }
    for (int i = t; i < 64 * 28; i += 320) {
        int r = i / 28, k = 100 + i % 28;
        Xs[swz2(r, k)] = 0;
    }
    __syncthreads();

    int wv = t >> 6, lane = t & 63, lr = lane & 15, lq = lane >> 4;
    bf8_t A[4][4];
    #pragma unroll
    for (int ks = 0; ks < 4; ++ks)
        #pragma unroll
        for (int mi = 0; mi < 4; ++mi) {
            int r = mi * 16 + lr;
            int g = (ks * 4 + lq) ^ (r & 7);
            A[ks][mi] = *(const bf8_t*)&Xs[r * KP2 + g * 8];
        }

    const float scaleq = 0.22360679774997896f;  // 1/sqrt(20)
    #pragma unroll
    for (int p = 0; p < 3; ++p) {
        f32x4 acc[4][5];
        #pragma unroll
        for (int mi = 0; mi < 4; ++mi)
            #pragma unroll
            for (int nj = 0; nj < 5; ++nj)
                acc[mi][nj] = (f32x4){0.f, 0.f, 0.f, 0.f};
        #pragma unroll
        for (int ks = 0; ks < 4; ++ks) {
            bf8_t b[5];
            #pragma unroll
            for (int nj = 0; nj < 5; ++nj) {
                const unsigned short* bp = Bp + ((size_t)((p * 25 + wv * 5 + nj) * QKV_KS + ks) * 64 + lane) * 8;
                b[nj] = *(const bf8_t*)bp;
            }
            #pragma unroll
            for (int mi = 0; mi < 4; ++mi)
                #pragma unroll
                for (int nj = 0; nj < 5; ++nj)
                    acc[mi][nj] = __builtin_amdgcn_mfma_f32_16x16x32_bf16(A[ks][mi], b[nj], acc[mi][nj], 0, 0, 0);
        }
        const float* bias = (p == 0) ? bq : (p == 1) ? bk : bv;
        unsigned short* op = (p == 0) ? qo : (p == 1) ? ko : vo;
        #pragma unroll
        for (int nj = 0; nj < 5; ++nj) {
            int cm = (wv * 5 + nj) * 16 + lr;
            int hh = cm / 20, dk = cm % 20;
            float bb = bias[cm];
            #pragma unroll
            for (int mi = 0; mi < 4; ++mi) {
                int Rq = R0 + mi * 16 + lq * 4;   // 4 consecutive rows
                int b  = Rq / 50, l0 = Rq - b * 50;
                float vle[4];
                #pragma unroll
                for (int j = 0; j < 4; ++j) {
                    float x = acc[mi][nj][j] + bb;
                    vle[j] = (p == 0) ? x * scaleq : x;
                }
                if (l0 <= 46) {
                    size_t base = (((size_t)b * H_ + hh) * DK_ + dk) * (size_t)L_ + l0;
                    unsigned int u0 = (unsigned int)f2bf(vle[0]) | ((unsigned int)f2bf(vle[1]) << 16);
                    unsigned int u1 = (unsigned int)f2bf(vle[2]) | ((unsigned int)f2bf(vle[3]) << 16);
                    *(unsigned int*)(op + base)     = u0;
                    *(unsigned int*)(op + base + 2) = u1;
                } else {
                    #pragma unroll
                    for (int j = 0; j < 4; ++j) {
                        int R = Rq + j;
                        int bj = R / 50, lj = R - bj * 50;
                        op[(((size_t)bj * H_ + hh) * DK_ + dk) * (size_t)L_ + lj] = f2bf(vle[j]);
                    }
                }
            }
        }
    }
}

// ---------------------------------------------------------------------------
// K2c: attention, single-pass (scores ~0.2, exp without max-shift is safe).
// ---------------------------------------------------------------------------
__global__ __launch_bounds__(256) void k_attn(const unsigned short* __restrict__ q,
                                              const unsigned short* __restrict__ k,
                                              const unsigned short* __restrict__ v,
                                              unsigned short* __restrict__ mh) {
    __shared__ float ks_[4][DK_][L_ + 2];
    __shared__ float vs_[4][DK_][L_ + 2];
    int t = threadIdx.x, wv = t >> 6, lane = t & 63;
    int bh = blockIdx.x * 4 + wv;
    int bl = bh / H_, hh = bh % H_;
    size_t base = (size_t)bh * (DK_ * L_); // [bl][hh][j][l] flat
    for (int i4 = lane * 4; i4 < DK_ * L_; i4 += 256) {
        uint2 kw = *(const uint2*)(k + base + i4);
        uint2 vw = *(const uint2*)(v + base + i4);
        unsigned short ku[4] = {(unsigned short)kw.x, (unsigned short)(kw.x >> 16),
                                (unsigned short)kw.y, (unsigned short)(kw.y >> 16)};
        unsigned short vu[4] = {(unsigned short)vw.x, (unsigned short)(vw.x >> 16),
                                (unsigned short)vw.y, (unsigned short)(vw.y >> 16)};
        #pragma unroll
        for (int e = 0; e < 4; ++e) {
            int idx = i4 + e;
            int j = idx / L_, m = idx - j * L_;
            ks_[wv][j][m] = bf2f(ku[e]);
            vs_[wv][j][m] = bf2f(vu[e]);
        }
    }
    int l = (lane < L_) ? lane : (L_ - 1);
    float qr[20];
    #pragma unroll
    for (int j = 0; j < DK_; ++j)
        qr[j] = bf2f(q[base + j * L_ + l]);
    __syncthreads();

    float sum = 0.f;
    float acc[20];
    #pragma unroll
    for (int j = 0; j < DK_; ++j) acc[j] = 0.f;
    #pragma unroll 2
    for (int m = 0; m < L_; ++m) {
        float a0 = 0.f, a1 = 0.f;
        #pragma unroll
        for (int j = 0; j < DK_; j += 2) {
            a0 = fmaf(qr[j],     ks_[wv][j][m],     a0);
            a1 = fmaf(qr[j + 1], ks_[wv][j + 1][m], a1);
        }
        float e = __expf(a0 + a1);
        sum += e;
        #pragma unroll
        for (int j = 0; j < DK_; ++j)
            acc[j] = fmaf(e, vs_[wv][j][m], acc[j]);
    }
    float inv = 1.f / sum;
    if (lane < L_) {
        unsigned int w_[10];
        #pragma unroll
        for (int j2 = 0; j2 < 10; ++j2) {
            unsigned short u0 = f2bf(tanhf(acc[j2 * 2] * inv));
            unsigned short u1 = f2bf(tanhf(acc[j2 * 2 + 1] * inv));
            w_[j2] = (unsigned int)u0 | ((unsigned int)u1 << 16);
        }
        unsigned short* dst = mh + ((size_t)bl * L_ + l) * MD_ + hh * DK_;
        uint2* d2 = (uint2*)dst;
        #pragma unroll
        for (int i = 0; i < 5; ++i) d2[i] = make_uint2(w_[2 * i], w_[2 * i + 1]);
    }
}

// ---------------------------------------------------------------------------
// K3: word additive attention via MFMA (unchanged)
// ---------------------------------------------------------------------------
__global__ __launch_bounds__(256) void k_watt_mfma(const unsigned short* __restrict__ mh,
                                                   const unsigned short* __restrict__ Bwa,
                                                   const float* __restrict__ bwa,
                                                   const float* __restrict__ qwa,
                                                   float* __restrict__ word_rep) {
    __shared__ unsigned short Xs[64 * KPA];   // 57.3 KB
    __shared__ float att2[64];
    __shared__ float alpha_s[64];
    int t = threadIdx.x;
    int b = blockIdx.x;
    for (int u = t; u < 64 * 52; u += 256) {
        int r = u / 52, gl = u % 52;
        uint4 w = make_uint4(0u, 0u, 0u, 0u);
        if (r < 50 && gl < 50)
            w = *(const uint4*)(mh + (size_t)b * (L_ * MD_) + r * MD_ + gl * 8);
        *(uint4*)&Xs[r * KPA + ((gl ^ (r & 7)) << 3)] = w;
    }
    if (t < 64) att2[t] = 0.f;
    __syncthreads();

    int wv = t >> 6, lane = t & 63, lr = lane & 15, lq = lane >> 4;
    f32x4 acc[4][4];
    #pragma unroll
    for (int mi = 0; mi < 4; ++mi)
        #pragma unroll
        for (int c = 0; c < 4; ++c) acc[mi][c] = (f32x4){0.f, 0.f, 0.f, 0.f};

    for (int ks = 0; ks < 13; ++ks) {
        bf8_t a[4], bb[4];
        #pragma unroll
        for (int mi = 0; mi < 4; ++mi) {
            int r = mi * 16 + lr;
            int g = (ks * 4 + lq) ^ (r & 7);
            a[mi] = *(const bf8_t*)&Xs[r * KPA + g * 8];
        }
        #pragma unroll
        for (int c = 0; c < 4; ++c) {
            int nt = wv * 4 + c;
            bb[c] = *(const bf8_t*)(Bwa + ((size_t)(nt * 13 + ks) * 64 + lane) * 8);
        }
        #pragma unroll
        for (int mi = 0; mi < 4; ++mi)
            #pragma unroll
            for (int c = 0; c < 4; ++c)
                acc[mi][c] = __builtin_amdgcn_mfma_f32_16x16x32_bf16(a[mi], bb[c], acc[mi][c], 0, 0, 0);
    }

    float pr[4][4];
    #pragma unroll
    for (int mi = 0; mi < 4; ++mi)
        #pragma unroll
        for (int j = 0; j < 4; ++j) pr[mi][j] = 0.f;
    #pragma unroll
    for (int c = 0; c < 4; ++c) {
        int col = (wv * 4 + c) * 16 + lr;
        float bv = (col < QD_) ? bwa[col] : 0.f;
        float qv = (col < QD_) ? qwa[col] : 0.f;
        #pragma unroll
        for (int mi = 0; mi < 4; ++mi) {
            #pragma unroll
            for (int j = 0; j < 4; ++j)
                pr[mi][j] = fmaf(tanhf(acc[mi][c][j] + bv), qv, pr[mi][j]);
        }
    }
    #pragma unroll
    for (int mi = 0; mi < 4; ++mi) {
        #pragma unroll
        for (int j = 0; j < 4; ++j) {
            float v = pr[mi][j];
            v += __shfl_xor(v, 1); v += __shfl_xor(v, 2);
            v += __shfl_xor(v, 4); v += __shfl_xor(v, 8);
            if (lr == 0) atomicAdd(&att2[mi * 16 + lq * 4 + j], v);
        }
    }
    __syncthreads();
    if (t == 0) {
        float mx = -1e30f;
        for (int l = 0; l < L_; ++l) mx = fmaxf(mx, att2[l]);
        float s = 0.f;
        for (int l = 0; l < L_; ++l) { float e = expf(att2[l] - mx); alpha_s[l] = e; s += e; }
        float inv = 1.f / s;
        for (int l = 0; l < L_; ++l) alpha_s[l] *= inv;
    }
    __syncthreads();
    for (int d = t; d < MD_; d += 256) {
        int glb = (d >> 3), jd = d & 7;
        float a = 0.f;
        for (int l = 0; l < L_; ++l)
            a = fmaf(alpha_s[l], bf2f(Xs[l * KPA + ((glb ^ (l & 7)) << 3) + jd]), a);
        word_rep[(size_t)b * MD_ + d] = a;
    }
}

// ---------------------------------------------------------------------------
// K5a: hAb[ge][c] = ent[ge] @ A1[0:100] + a1b   (MFMA, M=64 rows/block)
// ---------------------------------------------------------------------------
__global__ __launch_bounds__(320) void k_hab(const float* __restrict__ ent_emb,
                                             const unsigned short* __restrict__ Bh,
                                             const float* __restrict__ a1b,
                                             float* __restrict__ hAb) {
    __shared__ unsigned short Xs[64 * KP2];   // 16 KB
    int t = threadIdx.x;
    int R0 = blockIdx.x * 64;
    for (int c = t; c < 64 * 25; c += 320) {
        int r = c / 25, d4 = (c % 25) * 4;
        float4 f = *(const float4*)(ent_emb + (size_t)(R0 + r) * 100 + d4);
        uint2 w;
        w.x = pk2(f.x, f.y);
        w.y = pk2(f.z, f.w);
        *(uint2*)&Xs[swz2(r, d4)] = w;
    }
    for (int c = t; c < 64 * 7; c += 320) {
        int r = c / 7, k = 100 + (c % 7) * 4;
        *(uint2*)&Xs[swz2(r, k)] = make_uint2(0u, 0u);
    }
    __syncthreads();

    int wv = t >> 6, lane = t & 63, lr = lane & 15, lq = lane >> 4;
    bf8_t A[4][4];
    #pragma unroll
    for (int ks = 0; ks < 4; ++ks)
        #pragma unroll
        for (int mi = 0; mi < 4; ++mi) {
            int r = mi * 16 + lr;
            int g = (ks * 4 + lq) ^ (r & 7);
            A[ks][mi] = *(const bf8_t*)&Xs[r * KP2 + g * 8];
        }
    f32x4 acc[4][5];
    #pragma unroll
    for (int mi = 0; mi < 4; ++mi)
        #pragma unroll
        for (int nj = 0; nj < 5; ++nj)
            acc[mi][nj] = (f32x4){0.f, 0.f, 0.f, 0.f};
    #pragma unroll
    for (int ks = 0; ks < 4; ++ks) {
        bf8_t b[5];
        #pragma unroll
        for (int nj = 0; nj < 5; ++nj) {
            const unsigned short* bp = Bh + ((size_t)((wv * 5 + nj) * 4 + ks) * 64 + lane) * 8;
            b[nj] = *(const bf8_t*)bp;
        }
        #pragma unroll
        for (int mi = 0; mi < 4; ++mi)
            #pragma unroll
            for (int nj = 0; nj < 5; ++nj)
                acc[mi][nj] = __builtin_amdgcn_mfma_f32_16x16x32_bf16(A[ks][mi], b[nj], acc[mi][nj], 0, 0, 0);
    }
    #pragma unroll
    for (int nj = 0; nj < 5; ++nj) {
        int col = (wv * 5 + nj) * 16 + lr;
        float bb = a1b[col];
        #pragma unroll
        for (int mi = 0; mi < 4; ++mi) {
            int row = R0 + mi * 16 + lq * 4;
            #pragma unroll
            for (int j = 0; j < 4; ++j)
                hAb[(size_t)(row + j) * MD_ + col] = acc[mi][nj][j] + bb;
        }
    }
}

// ---------------------------------------------------------------------------
// K5c: KGAT v8 (R13-proven config): 16 groups/640 threads, A-frag consumption
// loop fully unrolled (static Af index -> registers, no scratch), 5 N-passes.
// ---------------------------------------------------------------------------
__global__ __launch_bounds__(640, 2) void k_kgat8(const float* __restrict__ ne,
                                               const float* __restrict__ nr,
                                               const unsigned short* __restrict__ Btr,
                                               const float* __restrict__ hAb,
                                               const float* __restrict__ A2,
                                               float* __restrict__ agg_g) {
    __shared__ float hab_s[G6][MD_];     // 25.6 KB
    __shared__ float att_s[MR6];
    __shared__ float alpha_s[MR6];
    __shared__ float gmx[G6], ginv[G6];
    int t = threadIdx.x;
    int ge0 = blockIdx.x * G6;

    for (int i = t; i < G6 * MD_; i += 640)
        ((float*)hab_s)[i] = hAb[(size_t)ge0 * MD_ + i];
    for (int i = t; i < MR6; i += 640) att_s[i] = 0.f;
    __syncthreads();

    int wv = t >> 6, lane = t & 63;
    int lr = lane & 15, lq = lane >> 4;
    const float* nep[2];
    const float* nrp[2];
    #pragma unroll
    for (int mi = 0; mi < 2; ++mi) {
        int r = (wv * 2 + mi) * 16 + lr;
        int g = (r * 3277) >> 16;            // r/20 for r<320
        int n = r - g * 20;
        size_t rb = ((size_t)(ge0 + g) * N_ + n) * ED_;
        nep[mi] = ne + rb;
        nrp[mi] = nr + rb;
    }
    int k0base = lq * 8;

    // ---- A-fragments loaded ONCE into registers (statically indexed below) ----
    bf8_t Af[2][KS3];
    #pragma unroll
    for (int ks = 0; ks < KS3; ++ks) {
        int k0 = ks * 32 + k0base;
        #pragma unroll
        for (int mi = 0; mi < 2; ++mi) {
            float4 f0, f1;
            if (k0 <= 92) {
                f0 = *(const float4*)(nep[mi] + k0);
                f1 = *(const float4*)(nep[mi] + k0 + 4);
            } else if (k0 == 96) {
                f0 = *(const float4*)(nep[mi] + 96);
                f1 = *(const float4*)(nrp[mi]);
            } else if (k0 <= 192) {
                f0 = *(const float4*)(nrp[mi] + k0 - 100);
                f1 = *(const float4*)(nrp[mi] + k0 - 96);
            } else {
                f0 = make_float4(0.f, 0.f, 0.f, 0.f);
                f1 = f0;
            }
            uint4 uu = make_uint4(pk2(f0.x, f0.y), pk2(f0.z, f0.w),
                                  pk2(f1.x, f1.y), pk2(f1.z, f1.w));
            Af[mi][ks] = *reinterpret_cast<bf8_t*>(&uu);
        }
    }

    #pragma unroll 1
    for (int p = 0; p < 5; ++p) {
        f32x4 acc[2][5];
        #pragma unroll
        for (int mi = 0; mi < 2; ++mi)
            #pragma unroll
            for (int nj = 0; nj < 5; ++nj)
                acc[mi][nj] = (f32x4){0.f, 0.f, 0.f, 0.f};
        #pragma unroll
        for (int ks = 0; ks < KS3; ++ks) {          // FULLY UNROLLED: static Af idx
            bf8_t b[5];
            #pragma unroll
            for (int nj = 0; nj < 5; ++nj) {
                int nt = p * 5 + nj;
                b[nj] = *(const bf8_t*)(Btr + ((size_t)(nt * KS3 + ks) * 64 + lane) * 8);
            }
            #pragma unroll
            for (int mi = 0; mi < 2; ++mi)
                #pragma unroll
                for (int nj = 0; nj < 5; ++nj)
                    acc[mi][nj] = __builtin_amdgcn_mfma_f32_16x16x32_bf16(Af[mi][ks], b[nj], acc[mi][nj], 0, 0, 0);
        }
        // per-pass epilogue: relu -> .A2 -> shfl reduce -> atomicAdd
        float pr[2][4];
        #pragma unroll
        for (int mi = 0; mi < 2; ++mi)
            #pragma unroll
            for (int j = 0; j < 4; ++j) pr[mi][j] = 0.f;
        #pragma unroll
        for (int nj = 0; nj < 5; ++nj) {
            int col = (p * 5 + nj) * 16 + lr;
            float a2v = A2[col];
            #pragma unroll
            for (int mi = 0; mi < 2; ++mi) {
                #pragma unroll
                for (int j = 0; j < 4; ++j) {
                    int row = (wv * 2 + mi) * 16 + lq * 4 + j;
                    int g = (row * 3277) >> 16;
                    float y = acc[mi][nj][j] + hab_s[g][col];
                    pr[mi][j] = fmaf(fmaxf(y, 0.f), a2v, pr[mi][j]);
                }
            }
        }
        #pragma unroll
        for (int mi = 0; mi < 2; ++mi) {
            #pragma unroll
            for (int j = 0; j < 4; ++j) {
                float v = pr[mi][j];
                v += __shfl_xor(v, 1); v += __shfl_xor(v, 2);
                v += __shfl_xor(v, 4); v += __shfl_xor(v, 8);
                if (lr == 0) atomicAdd(&att_s[(wv * 2 + mi) * 16 + lq * 4 + j], v);
            }
        }
    }
    __syncthreads();

    if (t < G6) {
        float mx = -1e30f;
        for (int n = 0; n < N_; ++n) mx = fmaxf(mx, att_s[t * N_ + n]);
        float s = 0.f;
        for (int n = 0; n < N_; ++n) s += expf(att_s[t * N_ + n] - mx);
        gmx[t] = mx; ginv[t] = 1.f / s;
    }
    __syncthreads();
    if (t < MR6) alpha_s[t] = expf(att_s[t] - gmx[t / N_]) * ginv[t / N_];
    __syncthreads();

    // agg[g][d] = sum_n alpha * ne[g][n][d]  (f32 direct, L2-hot)
    for (int i = t; i < G6 * ED_; i += 640) {
        int g = i / ED_, d = i % ED_;
        const float* np = ne + ((size_t)(ge0 + g) * N_) * ED_ + d;
        float aS = 0.f;
        #pragma unroll 4
        for (int n = 0; n < N_; ++n)
            aS = fmaf(alpha_s[g * N_ + n], np[(size_t)n * ED_], aS);
        agg_g[(size_t)(ge0 + g) * ED_ + d] = aS;
    }
}

// ---------------------------------------------------------------------------
// K5d: he = tanh([ent | agg] @ We1 + be1) via MFMA (unchanged)
// ---------------------------------------------------------------------------
__global__ __launch_bounds__(256) void k_he(const float* __restrict__ ent_emb,
                                            const float* __restrict__ agg_g,
                                            const unsigned short* __restrict__ BWe1,
                                            const float* __restrict__ be1,
                                            float* __restrict__ he) {
    __shared__ unsigned short Xs[64 * KP3];   // 32 KB
    int t = threadIdx.x;
    int R0 = blockIdx.x * 64;
    for (int c = t; c < 64 * 25; c += 256) {
        int r = c / 25, d4 = (c % 25) * 4;
        float4 f = *(const float4*)(ent_emb + (size_t)(R0 + r) * 100 + d4);
        uint2 w;
        w.x = pk2(f.x, f.y);
        w.y = pk2(f.z, f.w);
        *(uint2*)&Xs[swz3(r, d4)] = w;
        float4 g = *(const float4*)(agg_g + (size_t)(R0 + r) * 100 + d4);
        uint2 w2;
        w2.x = pk2(g.x, g.y);
        w2.y = pk2(g.z, g.w);
        *(uint2*)&Xs[swz3(r, 112 + d4)] = w2;
    }
    for (int c = t; c < 64 * 6; c += 256) {
        int r = c / 6, z = c % 6;
        int k = (z < 3) ? (100 + z * 4) : (212 + (z - 3) * 4);
        *(uint2*)&Xs[swz3(r, k)] = make_uint2(0u, 0u);
    }
    __syncthreads();

    int wv = t >> 6, lane = t & 63, lr = lane & 15, lq = lane >> 4;
    int rb = wv * 16;
    bf8_t A[7];
    #pragma unroll
    for (int ks = 0; ks < 7; ++ks) {
        int r = rb + lr;
        int g = (ks * 4 + lq) ^ (r & 7);
        A[ks] = *(const bf8_t*)&Xs[r * KP3 + g * 8];
    }
    f32x4 acc[7];
    #pragma unroll
    for (int nt = 0; nt < 7; ++nt) acc[nt] = (f32x4){0.f, 0.f, 0.f, 0.f};
    #pragma unroll
    for (int ks = 0; ks < 7; ++ks) {
        bf8_t b[7];
        #pragma unroll
        for (int nt = 0; nt < 7; ++nt)
            b[nt] = *(const bf8_t*)(BWe1 + ((size_t)(nt * 7 + ks) * 64 + lane) * 8);
        #pragma unroll
        for (int nt = 0; nt < 7; ++nt)
            acc[nt] = __builtin_amdgcn_mfma_f32_16x16x32_bf16(A[ks], b[nt], acc[nt], 0, 0, 0);
    }
    #pragma unroll
    for (int nt = 0; nt < 7; ++nt) {
        int col = nt * 16 + lr;
        if (col < 100) {
            float bb = be1[col];
            #pragma unroll
            for (int j = 0; j < 4; ++j) {
                int row = rb + lq * 4 + j;
                he[(size_t)(R0 + row) * 100 + col] = tanhf(acc[nt][j] + bb);
            }
        }
    }
}

// ---------------------------------------------------------------------------
// K7: fused tail — cat/sub MLPs + entity head + 4-view additive attention.
// ---------------------------------------------------------------------------
__global__ __launch_bounds__(256) void k_fuse_all(
        const float* __restrict__ word_rep, const float* __restrict__ he,
        const float* __restrict__ emb_c, const float* __restrict__ Wc1, const float* __restrict__ bc1,
        const float* __restrict__ Wc2, const float* __restrict__ bc2,
        const float* __restrict__ emb_s, const float* __restrict__ Ws1, const float* __restrict__ bs1,
        const float* __restrict__ Ws2, const float* __restrict__ bs2,
        const float* __restrict__ Wg, const float* __restrict__ bg,
        const float* __restrict__ Wfa, const float* __restrict__ bfa, const float* __restrict__ qfa,
        const int* __restrict__ cat_idx, const int* __restrict__ sub_idx,
        float* __restrict__ out_pre) {
    int b = blockIdx.x;
    __shared__ float reps[4][MD_];
    __shared__ float tin[100], th[100];
    __shared__ float alpha_s[4];
    __shared__ float red[4][4];
    int t = threadIdx.x, wave = t >> 6, lane = t & 63;

    // view 0: word (precomputed)
    for (int i = t; i < MD_; i += 256) reps[0][i] = word_rep[(size_t)b * MD_ + i];
    // view 1: entity = tanh(relu(mean_e(he[b]) @ Wg + bg))
    if (t < 100) {
        float a = 0.f;
        for (int e = 0; e < E_; ++e) a += he[((size_t)b * E_ + e) * ED_ + t];
        tin[t] = a * (1.f / E_);
    }
    __syncthreads();
    for (int m = t; m < MD_; m += 256) {
        float a = bg[m];
        for (int k = 0; k < ED_; ++k) a = fmaf(tin[k], Wg[k * MD_ + m], a);
        reps[1][m] = tanhf(fmaxf(a, 0.f));
    }
    __syncthreads();
    // view 2: category MLP
    if (t < 100) tin[t] = emb_c[(size_t)cat_idx[b] * 100 + t];
    __syncthreads();
    if (t < 100) {
        float a = bc1[t];
        for (int k = 0; k < 100; ++k) a = fmaf(tin[k], Wc1[k * 100 + t], a);
        th[t] = a;
    }
    __syncthreads();
    for (int m = t; m < MD_; m += 256) {
        float a = bc2[m];
        for (int k = 0; k < 100; ++k) a = fmaf(th[k], Wc2[k * MD_ + m], a);
        reps[2][m] = tanhf(a);
    }
    __syncthreads();
    // view 3: subcategory MLP
    if (t < 100) tin[t] = emb_s[(size_t)sub_idx[b] * 100 + t];
    __syncthreads();
    if (t < 100) {
        float a = bs1[t];
        for (int k = 0; k < 100; ++k) a = fmaf(tin[k], Ws1[k * 100 + t], a);
        th[t] = a;
    }
    __syncthreads();
    for (int m = t; m < MD_; m += 256) {
        float a = bs2[m];
        for (int k = 0; k < 100; ++k) a = fmaf(th[k], Ws2[k * MD_ + m], a);
        reps[3][m] = tanhf(a);
    }
    __syncthreads();

    // additive attention over the 4 views
    float p[4] = {0.f, 0.f, 0.f, 0.f};
    if (t < QD_) {
        float acc0 = bfa[t], acc1 = acc0, acc2 = acc0, acc3 = acc0;
        for (int d = 0; d < MD_; ++d) {
            float w = Wfa[d * QD_ + t];
            acc0 = fmaf(reps[0][d], w, acc0);
            acc1 = fmaf(reps[1][d], w, acc1);
            acc2 = fmaf(reps[2][d], w, acc2);
            acc3 = fmaf(reps[3][d], w, acc3);
        }
        float qv = qfa[t];
        p[0] = tanhf(acc0) * qv; p[1] = tanhf(acc1) * qv;
        p[2] = tanhf(acc2) * qv; p[3] = tanhf(acc3) * qv;
    }
    #pragma unroll
    for (int i = 0; i < 4; ++i) {
        float v = p[i];
        for (int o = 32; o > 0; o >>= 1) v += __shfl_down(v, o);
        if (lane == 0) red[i][wave] = v;
    }
    __syncthreads();
    if (t == 0) {
        float a4[4]; float mx = -1e30f;
        #pragma unroll
        for (int i = 0; i < 4; ++i) { a4[i] = red[i][0] + red[i][1] + red[i][2] + red[i][3]; mx = fmaxf(mx, a4[i]); }
        float s = 0.f;
        #pragma unroll
        for (int i = 0; i < 4; ++i) { a4[i] = expf(a4[i] - mx); s += a4[i]; }
        float inv = 1.f / s;
        #pragma unroll
        for (int i = 0; i < 4; ++i) alpha_s[i] = a4[i] * inv;
    }
    __syncthreads();
    for (int m = t; m < MD_; m += 256)
        out_pre[(size_t)b * MD_ + m] = alpha_s[0] * reps[0][m] + alpha_s[1] * reps[1][m]
                                     + alpha_s[2] * reps[2][m] + alpha_s[3] * reps[3][m];
}

// ---------------------------------------------------------------------------
// K8: batchnorm over batch axis (unchanged)
// ---------------------------------------------------------------------------
__global__ __launch_bounds__(256) void k_bn(float* __restrict__ x,
                                            const float* __restrict__ gamma,
                                            const float* __restrict__ beta) {
    int m = blockIdx.x;
    int t = threadIdx.x, wave = t >> 6, lane = t & 63;
    __shared__ float red1[4], red2[4];
    float v[4];
    float s1 = 0.f, s2 = 0.f;
    #pragma unroll
    for (int i = 0; i < 4; ++i) {
        v[i] = x[(size_t)(t + i * 256) * MD_ + m];
        s1 += v[i];
        s2 = fmaf(v[i], v[i], s2);
    }
    for (int o = 32; o > 0; o >>= 1) { s1 += __shfl_down(s1, o); s2 += __shfl_down(s2, o); }
    if (lane == 0) { red1[wave] = s1; red2[wave] = s2; }
    __syncthreads();
    float mean = (red1[0] + red1[1] + red1[2] + red1[3]) * (1.f / 1024.f);
    float var  = (red2[0] + red2[1] + red2[2] + red2[3]) * (1.f / 1024.f) - mean * mean;
    float scale = rsqrtf(var + 1e-5f) * gamma[m];
    float bb = beta[m];
    #pragma unroll
    for (int i = 0; i < 4; ++i)
        x[(size_t)(t + i * 256) * MD_ + m] = (v[i] - mean) * scale + bb;
}

// ---------------------------------------------------------------------------
extern "C" void kernel_launch(void* const* d_in, const int* in_sizes, int n_in,
                              void* d_out, int out_size, void* d_ws, size_t ws_size,
                              hipStream_t stream) {
    const float* word_emb = (const float*)d_in[0];
    const float* ent_emb  = (const float*)d_in[1];
    const float* ne       = (const float*)d_in[2];
    const float* nr       = (const float*)d_in[3];
    const float* emb_c    = (const float*)d_in[4];
    const float* Wc1 = (const float*)d_in[5];
    const float* bc1 = (const float*)d_in[6];
    const float* Wc2 = (const float*)d_in[7];
    const float* bc2 = (const float*)d_in[8];
    const float* emb_s = (const float*)d_in[9];
    const float* Ws1 = (const float*)d_in[10];
    const float* bs1 = (const float*)d_in[11];
    const float* Ws2 = (const float*)d_in[12];
    const float* bs2 = (const float*)d_in[13];
    const float* Ww1 = (const float*)d_in[14];
    const float* bw1 = (const float*)d_in[15];
    const float* Wq  = (const float*)d_in[16];
    const float* bq  = (const float*)d_in[17];
    const float* Wk  = (const float*)d_in[18];
    const float* bk  = (const float*)d_in[19];
    const float* Wv  = (const float*)d_in[20];
    const float* bv  = (const float*)d_in[21];
    const float* Wwa = (const float*)d_in[22];
    const float* bwa = (const float*)d_in[23];
    const float* qwa = (const float*)d_in[24];
    const float* A1  = (const float*)d_in[25];
    const float* a1b = (const float*)d_in[26];
    const float* A2  = (const float*)d_in[27];
    const float* We1 = (const float*)d_in[29];
    const float* be1 = (const float*)d_in[30];
    const float* Wg  = (const float*)d_in[31];
    const float* bg  = (const float*)d_in[32];
    const float* Wfa = (const float*)d_in[36];
    const float* bfa = (const float*)d_in[37];
    const float* qfa = (const float*)d_in[38];
    const float* gamma = (const float*)d_in[39];
    const float* beta  = (const float*)d_in[40];
    const int* cat_idx = (const int*)d_in[41];
    const int* sub_idx = (const int*)d_in[42];

    // workspace (no aliasing; ~190 MB of ~655 MB available)
    char* p = (char*)d_ws;
    float* word_rep = (float*)p;  p += (size_t)B_ * MD_ * 4;               // 1.64 MB
    float* he       = (float*)p;  p += (size_t)B_ * E_ * ED_ * 4;          // 8.19 MB
    float* agg_g    = (float*)p;  p += (size_t)B_ * E_ * ED_ * 4;          // 8.19 MB
    float* hAb      = (float*)p;  p += (size_t)B_ * E_ * MD_ * 4;          // 32.77 MB
    unsigned short* Bqkv  = (unsigned short*)p; p += (size_t)QKV_NT * QKV_KS * 64 * 8 * 2;
    unsigned short* Bh    = (unsigned short*)p; p += (size_t)25 * 4 * 64 * 8 * 2;
    unsigned short* Btr   = (unsigned short*)p; p += (size_t)25 * KS3 * 64 * 8 * 2;
    unsigned short* BWe1  = (unsigned short*)p; p += (size_t)7 * 7 * 64 * 8 * 2;
    unsigned short* Bwlin = (unsigned short*)p; p += (size_t)8 * 10 * 64 * 8 * 2;
    unsigned short* Bwa   = (unsigned short*)p; p += (size_t)16 * 13 * 64 * 8 * 2;
    unsigned short* h_bf  = (unsigned short*)p; p += (size_t)B_ * L_ * 100 * 2;        // 10.24 MB
    unsigned short* qb    = (unsigned short*)p; p += (size_t)B_ * H_ * DK_ * L_ * 2;   // 40.96 MB
    unsigned short* kb    = (unsigned short*)p; p += (size_t)B_ * H_ * DK_ * L_ * 2;
    unsigned short* vb    = (unsigned short*)p; p += (size_t)B_ * H_ * DK_ * L_ * 2;
    unsigned short* mh_bf = (unsigned short*)p; p += (size_t)B_ * L_ * MD_ * 2;        // 40.96 MB
    float* out = (float*)d_out;

    k_pack_qkv<<<dim3(QKV_NT, QKV_KS), 64, 0, stream>>>(Wq, Wk, Wv, Bqkv);
    k_pack_A1part<<<dim3(25, 4), 64, 0, stream>>>(A1, Bh, 0, 100);
    k_pack_A1part<<<dim3(25, KS3), 64, 0, stream>>>(A1, Btr, 100, 200);
    k_pack_We1<<<dim3(7, 7), 64, 0, stream>>>(We1, BWe1);
    k_pack_wlin<<<dim3(8, 10), 64, 0, stream>>>(Ww1, Bwlin);
    k_pack_wwa<<<dim3(16, 13), 64, 0, stream>>>(Wwa, Bwa);
    k_wlin_mfma<<<(B_ * L_) / 64, 256, 0, stream>>>(word_emb, Bwlin, bw1, h_bf);
    k_qkv<<<(B_ * L_) / 64, 320, 0, stream>>>(h_bf, Bqkv, bq, bk, bv, qb, kb, vb);
    k_attn<<<(B_ * H_) / 4, 256, 0, stream>>>(qb, kb, vb, mh_bf);
    k_watt_mfma<<<B_, 256, 0, stream>>>(mh_bf, Bwa, bwa, qwa, word_rep);
    k_hab<<<(B_ * E_) / 64, 320, 0, stream>>>(ent_emb, Bh, a1b, hAb);
    k_kgat8<<<(B_ * E_) / G6, 640, 0, stream>>>(ne, nr, Btr, hAb, A2, agg_g);
    k_he<<<(B_ * E_) / 64, 256, 0, stream>>>(ent_emb, agg_g, BWe1, be1, he);
    k_fuse_all<<<B_, 256, 0, stream>>>(word_rep, he,
                                       emb_c, Wc1, bc1, Wc2, bc2,
                                       emb_s, Ws1, bs1, Ws2, bs2,
                                       Wg, bg, Wfa, bfa, qfa,
                                       cat_idx, sub_idx, out);
    k_bn<<<MD_, 256, 0, stream>>>(out, gamma, beta);
}